// Round 7
// baseline (923.573 us; speedup 1.0000x reference)
//
#include <hip/hip_runtime.h>
#include <math.h>

#define BB   8
#define CCH  256
#define HH   112
#define HW   12544   // 112*112
#define LDK  40      // fallback conv: padded k-stride in shorts

typedef __attribute__((ext_vector_type(8))) short  bf16x8;
typedef __attribute__((ext_vector_type(4))) short  short4v;
typedef __attribute__((ext_vector_type(4))) float  f32x4;

typedef __attribute__((address_space(1))) const void gm_cv;
typedef __attribute__((address_space(3))) void lds_v;

__device__ __forceinline__ unsigned short f2bf_rne(float f) {
    unsigned u = __float_as_uint(f);
    return (unsigned short)((u + 0x7FFFu + ((u >> 16) & 1u)) >> 16);
}
__device__ __forceinline__ float bf2f(unsigned short h) {
    return __uint_as_float(((unsigned)h) << 16);
}

// ---------------- pre-passes ----------------

__global__ __launch_bounds__(256) void w_prep(
    const float* __restrict__ w0, const float* __restrict__ w1,
    const float* __restrict__ w2, const float* __restrict__ w3,
    short* __restrict__ dst)   // 4 x (65536 hi + 65536 lo)
{
    const int which = blockIdx.y;
    const float* src = which == 0 ? w0 : which == 1 ? w1 : which == 2 ? w2 : w3;
    const int i = blockIdx.x * 256 + threadIdx.x;
    float v = src[i];
    unsigned short hb = f2bf_rne(v);
    dst[(size_t)which * 131072 + i]         = (short)hb;
    dst[(size_t)which * 131072 + 65536 + i] = (short)f2bf_rne(v - bf2f(hb));
}

// Transpose+convert: src [b][CCH][HW] fp32 -> dhi/dlo [b][HW][CCH] bf16.
__global__ __launch_bounds__(256) void t_prep(
    const float* __restrict__ src,
    short* __restrict__ dhi, short* __restrict__ dlo)
{
    __shared__ float Ts[32][33];
    const int n0 = blockIdx.x * 32;
    const int c0 = blockIdx.y * 32;
    const int b  = blockIdx.z;
    const int tx = threadIdx.x & 31, ty = threadIdx.x >> 5;
#pragma unroll
    for (int i = 0; i < 4; ++i) {
        int c = c0 + ty + 8 * i;
        Ts[ty + 8 * i][tx] = src[((size_t)b * CCH + c) * HW + n0 + tx];
    }
    __syncthreads();
#pragma unroll
    for (int i = 0; i < 4; ++i) {
        int n = n0 + ty + 8 * i;
        float v = Ts[tx][ty + 8 * i];
        unsigned short hb = f2bf_rne(v);
        size_t o = ((size_t)b * HW + n) * CCH + c0 + tx;
        dhi[o] = (short)hb;
        dlo[o] = (short)f2bf_rne(v - bf2f(hb));
    }
}

// ---------------- main conv: 2-phase double-buffered pipeline ----------------
// Y[b][o][n] = sum_c W[o][c]*X[b][c][n]; A=W hi/lo, B=Xt[b][n][c] hi/lo.
// 128x128 tile, BK=32, dbuf LDS (64 KiB -> 2 blocks/CU), counted vmcnt(8) +
// raw s_barrier: next tile's global_load_lds stay in flight through compute.
// XOR slot swizzle: physical slot = logical ^ ((row>>1)&3)  (16B slots).
__global__ __launch_bounds__(256, 2) void conv_dbuf(
    const short* __restrict__ Whi, const short* __restrict__ Wlo,
    const short* __restrict__ Xthi, const short* __restrict__ Xtlo,
    float* __restrict__ Yout, const float* __restrict__ Res)
{
    const int bm  = blockIdx.x;   // 0..1  (fastest: adjacent blocks share B in L2)
    const int bn  = blockIdx.y;   // 0..97
    const int b   = blockIdx.z;   // 0..7
    const int tid = threadIdx.x;
    const int lane = tid & 63, wid = tid >> 6;
    const int wr = wid >> 1, wc = wid & 1;
    const int fr = lane & 15, fg = lane >> 4;

    // [buf][hilo][row*32 + col]
    __shared__ __align__(16) short As[2][2][128 * 32];
    __shared__ __align__(16) short Bs[2][2][128 * 32];

    f32x4 acc[4][4];
#pragma unroll
    for (int m = 0; m < 4; ++m)
#pragma unroll
        for (int nf = 0; nf < 4; ++nf) acc[m][nf] = (f32x4){0.f, 0.f, 0.f, 0.f};

    // staging roles: 1 KiB chunk = 16 rows x 4 slots(16B). 8 chunks/plane.
    const int srow  = lane >> 2;                       // 0..15
    const int sslot = lane & 3;                        // 0..3
    const int scol  = ((sslot ^ ((srow >> 1) & 3)) << 3);  // pre-swizzled col (shorts)

    const size_t wbase = (size_t)bm * 128 * CCH;
    const size_t xbase = ((size_t)b * HW + (size_t)bn * 128) * CCH;

    auto STAGE = [&](int bi, int t) {
        const int k0 = t * 32;
#pragma unroll
        for (int j = 0; j < 2; ++j) {
            const int ch  = wid * 2 + j;               // 0..7
            const int row = ch * 16 + srow;            // 0..127
            const size_t wo = wbase + (size_t)row * CCH + k0 + scol;
            const size_t xo = xbase + (size_t)row * CCH + k0 + scol;
            __builtin_amdgcn_global_load_lds((gm_cv*)(Whi + wo),  (lds_v*)&As[bi][0][ch * 512], 16, 0, 0);
            __builtin_amdgcn_global_load_lds((gm_cv*)(Wlo + wo),  (lds_v*)&As[bi][1][ch * 512], 16, 0, 0);
            __builtin_amdgcn_global_load_lds((gm_cv*)(Xthi + xo), (lds_v*)&Bs[bi][0][ch * 512], 16, 0, 0);
            __builtin_amdgcn_global_load_lds((gm_cv*)(Xtlo + xo), (lds_v*)&Bs[bi][1][ch * 512], 16, 0, 0);
        }
    };

    auto COMPUTE = [&](int bi) {
        bf16x8 ah[4], al[4], bh[4], bl[4];
#pragma unroll
        for (int m = 0; m < 4; ++m) {
            const int row = wr * 64 + m * 16 + fr;
            const int off = row * 32 + ((fg ^ ((fr >> 1) & 3)) << 3);
            ah[m] = *(const bf16x8*)&As[bi][0][off];
            al[m] = *(const bf16x8*)&As[bi][1][off];
        }
#pragma unroll
        for (int nf = 0; nf < 4; ++nf) {
            const int row = wc * 64 + nf * 16 + fr;
            const int off = row * 32 + ((fg ^ ((fr >> 1) & 3)) << 3);
            bh[nf] = *(const bf16x8*)&Bs[bi][0][off];
            bl[nf] = *(const bf16x8*)&Bs[bi][1][off];
        }
#pragma unroll
        for (int m = 0; m < 4; ++m)
#pragma unroll
            for (int nf = 0; nf < 4; ++nf) {
                acc[m][nf] = __builtin_amdgcn_mfma_f32_16x16x32_bf16(ah[m], bh[nf], acc[m][nf], 0, 0, 0);
                acc[m][nf] = __builtin_amdgcn_mfma_f32_16x16x32_bf16(ah[m], bl[nf], acc[m][nf], 0, 0, 0);
                acc[m][nf] = __builtin_amdgcn_mfma_f32_16x16x32_bf16(al[m], bh[nf], acc[m][nf], 0, 0, 0);
            }
    };

    STAGE(0, 0);
    int cur = 0;
    for (int t = 0; t < 7; ++t) {
        STAGE(cur ^ 1, t + 1);
        // wait only the CURRENT tile's 8 loads (8 newest may stay in flight)
        asm volatile("s_waitcnt vmcnt(8)" ::: "memory");
        __builtin_amdgcn_s_barrier();
        __builtin_amdgcn_sched_barrier(0);
        COMPUTE(cur);
        __builtin_amdgcn_s_barrier();   // all waves done reading buf before overwrite
        cur ^= 1;
    }
    asm volatile("s_waitcnt vmcnt(0)" ::: "memory");
    __builtin_amdgcn_s_barrier();
    __builtin_amdgcn_sched_barrier(0);
    COMPUTE(cur);

    // epilogue: C/D layout col=lane&15, row=(lane>>4)*4+reg (verified r5)
#pragma unroll
    for (int m = 0; m < 4; ++m)
#pragma unroll
        for (int nf = 0; nf < 4; ++nf) {
            const int gcol = bn * 128 + wc * 64 + nf * 16 + fr;
#pragma unroll
            for (int q = 0; q < 4; ++q) {
                const int grow = bm * 128 + wr * 64 + m * 16 + fg * 4 + q;
                const size_t idx = ((size_t)b * CCH + grow) * HW + gcol;
                float v = acc[m][nf][q];
                if (Res) v = fmaxf(v + Res[idx], 0.f);
                Yout[idx] = v;
            }
        }
}

// ---------------- fallback conv (round-5, proven) ----------------
__global__ __launch_bounds__(256) void conv_mfma(
    const float* __restrict__ Wm,
    const float* __restrict__ Xin,
    float* __restrict__ Yout,
    const float* __restrict__ Res)
{
    const int bn  = blockIdx.x;
    const int bm  = blockIdx.y;
    const int b   = blockIdx.z;
    const int tid = threadIdx.x;

    __shared__ __align__(16) short As[2][128 * LDK];
    __shared__ __align__(16) short Bs[2][128 * LDK];

    const float* Xb = Xin + (size_t)b * CCH * HW;

    f32x4 acc[4][4];
#pragma unroll
    for (int m = 0; m < 4; ++m)
#pragma unroll
        for (int nf = 0; nf < 4; ++nf) acc[m][nf] = (f32x4){0.f, 0.f, 0.f, 0.f};

    const int ao  = tid >> 1;
    const int akh = (tid & 1) << 4;
    const int bnp = tid & 31;
    const int bcp = tid >> 5;

    const int lane = tid & 63;
    const int wid  = tid >> 6;
    const int wr = wid >> 1, wc = wid & 1;
    const int fr = lane & 15;
    const int fg = lane >> 4;

    for (int k0 = 0; k0 < CCH; k0 += 32) {
        {
            const float* wsrc = Wm + (size_t)(bm * 128 + ao) * CCH + k0 + akh;
            float4 w0 = *(const float4*)(wsrc + 0);
            float4 w1 = *(const float4*)(wsrc + 4);
            float4 w2 = *(const float4*)(wsrc + 8);
            float4 w3 = *(const float4*)(wsrc + 12);
            float wf[16] = {w0.x, w0.y, w0.z, w0.w, w1.x, w1.y, w1.z, w1.w,
                            w2.x, w2.y, w2.z, w2.w, w3.x, w3.y, w3.z, w3.w};
            bf16x8 h0, h1, l0, l1;
#pragma unroll
            for (int i = 0; i < 8; ++i) {
                unsigned short hb = f2bf_rne(wf[i]);
                h0[i] = (short)hb;
                l0[i] = (short)f2bf_rne(wf[i] - bf2f(hb));
            }
#pragma unroll
            for (int i = 0; i < 8; ++i) {
                unsigned short hb = f2bf_rne(wf[8 + i]);
                h1[i] = (short)hb;
                l1[i] = (short)f2bf_rne(wf[8 + i] - bf2f(hb));
            }
            *(bf16x8*)&As[0][ao * LDK + akh]     = h0;
            *(bf16x8*)&As[0][ao * LDK + akh + 8] = h1;
            *(bf16x8*)&As[1][ao * LDK + akh]     = l0;
            *(bf16x8*)&As[1][ao * LDK + akh + 8] = l1;
        }
        {
            const float* xsrc = Xb + (size_t)(k0 + bcp * 4) * HW + (size_t)bn * 128 + bnp * 4;
            float4 r0 = *(const float4*)(xsrc);
            float4 r1 = *(const float4*)(xsrc + HW);
            float4 r2 = *(const float4*)(xsrc + 2 * HW);
            float4 r3 = *(const float4*)(xsrc + 3 * HW);
            float rf[4][4] = {{r0.x, r0.y, r0.z, r0.w},
                              {r1.x, r1.y, r1.z, r1.w},
                              {r2.x, r2.y, r2.z, r2.w},
                              {r3.x, r3.y, r3.z, r3.w}};
#pragma unroll
            for (int j = 0; j < 4; ++j) {
                short4v hv, lv;
#pragma unroll
                for (int rr = 0; rr < 4; ++rr) {
                    unsigned short hb = f2bf_rne(rf[rr][j]);
                    hv[rr] = (short)hb;
                    lv[rr] = (short)f2bf_rne(rf[rr][j] - bf2f(hb));
                }
                *(short4v*)&Bs[0][(bnp * 4 + j) * LDK + bcp * 4] = hv;
                *(short4v*)&Bs[1][(bnp * 4 + j) * LDK + bcp * 4] = lv;
            }
        }
        __syncthreads();

        bf16x8 ah[4], al[4], bh[4], bl[4];
#pragma unroll
        for (int m = 0; m < 4; ++m) {
            const int off = (wr * 64 + m * 16 + fr) * LDK + fg * 8;
            ah[m] = *(const bf16x8*)&As[0][off];
            al[m] = *(const bf16x8*)&As[1][off];
        }
#pragma unroll
        for (int nf = 0; nf < 4; ++nf) {
            const int off = (wc * 64 + nf * 16 + fr) * LDK + fg * 8;
            bh[nf] = *(const bf16x8*)&Bs[0][off];
            bl[nf] = *(const bf16x8*)&Bs[1][off];
        }
#pragma unroll
        for (int m = 0; m < 4; ++m)
#pragma unroll
            for (int nf = 0; nf < 4; ++nf) {
                acc[m][nf] = __builtin_amdgcn_mfma_f32_16x16x32_bf16(ah[m], bh[nf], acc[m][nf], 0, 0, 0);
                acc[m][nf] = __builtin_amdgcn_mfma_f32_16x16x32_bf16(ah[m], bl[nf], acc[m][nf], 0, 0, 0);
                acc[m][nf] = __builtin_amdgcn_mfma_f32_16x16x32_bf16(al[m], bh[nf], acc[m][nf], 0, 0, 0);
            }
        __syncthreads();
    }

#pragma unroll
    for (int m = 0; m < 4; ++m)
#pragma unroll
        for (int nf = 0; nf < 4; ++nf) {
            const int gcol = bn * 128 + wc * 64 + nf * 16 + fr;
#pragma unroll
            for (int q = 0; q < 4; ++q) {
                const int grow = bm * 128 + wr * 64 + m * 16 + fg * 4 + q;
                const size_t idx = ((size_t)b * CCH + grow) * HW + gcol;
                float v = acc[m][nf][q];
                if (Res) v = fmaxf(v + Res[idx], 0.f);
                Yout[idx] = v;
            }
        }
}

// ---------------- attention (512 threads; template tag identifies path) ----
template <int PATH>
__global__ __launch_bounds__(512) void attn_k(
    const float* __restrict__ Qg,
    const float* __restrict__ Kg,
    const float* __restrict__ Vg,
    float* __restrict__ Zg)
{
    const int bc  = blockIdx.x;
    const int tid = threadIdx.x;
    const int tx  = tid & 15;
    const int ty  = tid >> 4;

    __shared__ float Qs[HH][116];  // later reused to hold M
    __shared__ float Ks[HH][116];
    __shared__ float Vs[HH][116];

    const float* Qp = Qg + (size_t)bc * HW;
    const float* Kp = Kg + (size_t)bc * HW;
    const float* Vp = Vg + (size_t)bc * HW;

    for (int idx = tid; idx < HW / 4; idx += 512) {
        int row = idx / 28;
        int c4  = (idx % 28) * 4;
        *(float4*)&Qs[row][c4] = *(const float4*)(Qp + row * HH + c4);
        *(float4*)&Ks[row][c4] = *(const float4*)(Kp + row * HH + c4);
        *(float4*)&Vs[row][c4] = *(const float4*)(Vp + row * HH + c4);
    }
    __syncthreads();

    const bool act = (ty < 28);
    const int i0 = ty * 4;
    const int j0 = tx * 7;

    float s[4][7];
    if (act) {
#pragma unroll
        for (int ii = 0; ii < 4; ++ii)
#pragma unroll
            for (int jj = 0; jj < 7; ++jj) s[ii][jj] = 0.f;

        for (int k = 0; k < HH; ++k) {
            float qv[4], kv[7];
#pragma unroll
            for (int ii = 0; ii < 4; ++ii) qv[ii] = Qs[i0 + ii][k];
#pragma unroll
            for (int jj = 0; jj < 7; ++jj) kv[jj] = Ks[k][j0 + jj];
#pragma unroll
            for (int ii = 0; ii < 4; ++ii)
#pragma unroll
                for (int jj = 0; jj < 7; ++jj)
                    s[ii][jj] = fmaf(qv[ii], kv[jj], s[ii][jj]);
        }

#pragma unroll
        for (int ii = 0; ii < 4; ++ii) {
            float mx = s[ii][0];
#pragma unroll
            for (int jj = 1; jj < 7; ++jj) mx = fmaxf(mx, s[ii][jj]);
#pragma unroll
            for (int off = 1; off < 16; off <<= 1) mx = fmaxf(mx, __shfl_xor(mx, off));
            float sum = 0.f;
#pragma unroll
            for (int jj = 0; jj < 7; ++jj) {
                float e = __expf(s[ii][jj] - mx);
                s[ii][jj] = e;
                sum += e;
            }
#pragma unroll
            for (int off = 1; off < 16; off <<= 1) sum += __shfl_xor(sum, off);
            float inv = 1.0f / sum;
#pragma unroll
            for (int jj = 0; jj < 7; ++jj) s[ii][jj] *= inv;
        }
    }

    __syncthreads();
    if (act) {
#pragma unroll
        for (int ii = 0; ii < 4; ++ii)
#pragma unroll
            for (int jj = 0; jj < 7; ++jj)
                Qs[i0 + ii][j0 + jj] = s[ii][jj];
    }
    __syncthreads();

    if (act) {
        float z[4][7];
#pragma unroll
        for (int ii = 0; ii < 4; ++ii)
#pragma unroll
            for (int ww = 0; ww < 7; ++ww) z[ii][ww] = 0.f;

        for (int j = 0; j < HH; ++j) {
            float mv[4], vv[7];
#pragma unroll
            for (int ii = 0; ii < 4; ++ii) mv[ii] = Qs[i0 + ii][j];
#pragma unroll
            for (int ww = 0; ww < 7; ++ww) vv[ww] = Vs[j][j0 + ww];
#pragma unroll
            for (int ii = 0; ii < 4; ++ii)
#pragma unroll
                for (int ww = 0; ww < 7; ++ww)
                    z[ii][ww] = fmaf(mv[ii], vv[ww], z[ii][ww]);
        }

        float* Zp = Zg + (size_t)bc * HW;
#pragma unroll
        for (int ii = 0; ii < 4; ++ii)
#pragma unroll
            for (int ww = 0; ww < 7; ++ww)
                Zp[(i0 + ii) * HH + j0 + ww] = z[ii][ww];
    }
}

extern "C" void kernel_launch(void* const* d_in, const int* in_sizes, int n_in,
                              void* d_out, int out_size, void* d_ws, size_t ws_size,
                              hipStream_t stream) {
    const float* x  = (const float*)d_in[0];
    const float* y  = (const float*)d_in[1];
    const float* WQ = (const float*)d_in[2];
    const float* WK = (const float*)d_in[3];
    const float* WV = (const float*)d_in[4];
    const float* WZ = (const float*)d_in[5];
    float* out = (float*)d_out;

    const size_t n = (size_t)BB * CCH * HW;        // 25,690,112 elements
    const size_t S_BYTES = n * 4;                  // 102.76 MB
    const size_t NEED = 3 * S_BYTES + (size_t)4 * CCH * CCH * 2 * sizeof(short);

    if (ws_size >= NEED) {
        short* At_hi = (short*)d_ws;
        short* At_lo = At_hi + n;
        float* Kb = (float*)((char*)d_ws + S_BYTES);
        float* Vb = (float*)((char*)d_ws + 2 * S_BYTES);
        short* Wb = (short*)((char*)d_ws + 3 * S_BYTES);
        float* Qb = out;
        float* Zb = Kb;

        dim3 tgrid(HW / 32, CCH / 32, BB);
        dim3 cgrid(2, 98, 8);

        w_prep<<<dim3(256, 4), 256, 0, stream>>>(WQ, WK, WV, WZ, Wb);
        t_prep<<<tgrid, 256, 0, stream>>>(x, At_hi, At_lo);
        conv_dbuf<<<cgrid, 256, 0, stream>>>(Wb, Wb + 65536, At_hi, At_lo, Qb, nullptr);
        t_prep<<<tgrid, 256, 0, stream>>>(y, At_hi, At_lo);
        conv_dbuf<<<cgrid, 256, 0, stream>>>(Wb + 131072, Wb + 131072 + 65536, At_hi, At_lo, Kb, nullptr);
        conv_dbuf<<<cgrid, 256, 0, stream>>>(Wb + 262144, Wb + 262144 + 65536, At_hi, At_lo, Vb, nullptr);
        attn_k<1><<<dim3(2048), 512, 0, stream>>>(Qb, Kb, Vb, Zb);
        t_prep<<<tgrid, 256, 0, stream>>>(Zb, At_hi, At_lo);
        conv_dbuf<<<cgrid, 256, 0, stream>>>(Wb + 393216, Wb + 393216 + 65536, At_hi, At_lo, out, x);
    } else {
        float* Kb = (float*)d_ws;
        float* Vb = Kb + n;
        float* Zb = Kb;
        float* Qb = out;
        dim3 grid(98, 2, 8);
        conv_mfma<<<grid, 256, 0, stream>>>(WQ, x, Qb, nullptr);
        conv_mfma<<<grid, 256, 0, stream>>>(WK, y, Kb, nullptr);
        conv_mfma<<<grid, 256, 0, stream>>>(WV, y, Vb, nullptr);
        attn_k<0><<<dim3(2048), 512, 0, stream>>>(Qb, Kb, Vb, Zb);
        conv_mfma<<<grid, 256, 0, stream>>>(WZ, Zb, out, x);
    }
}

// Round 8
// 824.017 us; speedup vs baseline: 1.1208x; 1.1208x over previous
//
#include <hip/hip_runtime.h>
#include <math.h>

#define BB   8
#define CCH  256
#define HH   112
#define HW   12544   // 112*112
#define LDK  40      // fallback conv: padded k-stride in shorts

typedef __attribute__((ext_vector_type(8))) short  bf16x8;
typedef __attribute__((ext_vector_type(4))) short  short4v;
typedef __attribute__((ext_vector_type(4))) float  f32x4;

typedef __attribute__((address_space(1))) const void gm_cv;
typedef __attribute__((address_space(3))) void lds_v;

__device__ __forceinline__ unsigned short f2bf_rne(float f) {
    unsigned u = __float_as_uint(f);
    return (unsigned short)((u + 0x7FFFu + ((u >> 16) & 1u)) >> 16);
}
__device__ __forceinline__ float bf2f(unsigned short h) {
    return __uint_as_float(((unsigned)h) << 16);
}

// ---------------- pre-passes (v2: 16B stores) ----------------

// weights: 4 x [256][256] fp32 -> bf16 hi/lo, 8 elems/thread, 16B stores
__global__ __launch_bounds__(256) void w_prep(
    const float* __restrict__ w0, const float* __restrict__ w1,
    const float* __restrict__ w2, const float* __restrict__ w3,
    short* __restrict__ dst)
{
    const int which = blockIdx.y;
    const float* src = which == 0 ? w0 : which == 1 ? w1 : which == 2 ? w2 : w3;
    const int base = (blockIdx.x * 256 + threadIdx.x) * 8;   // grid.x=32 -> <65536
    float4 a = *(const float4*)(src + base);
    float4 b = *(const float4*)(src + base + 4);
    float f[8] = {a.x, a.y, a.z, a.w, b.x, b.y, b.z, b.w};
    bf16x8 h, l;
#pragma unroll
    for (int e = 0; e < 8; ++e) {
        unsigned short hb = f2bf_rne(f[e]);
        h[e] = (short)hb;
        l[e] = (short)f2bf_rne(f[e] - bf2f(hb));
    }
    *(bf16x8*)&dst[(size_t)which * 131072 + base]         = h;
    *(bf16x8*)&dst[(size_t)which * 131072 + 65536 + base] = l;
}

// Transpose+convert: src [b][CCH][HW] fp32 -> dhi/dlo [b][HW][CCH] bf16.
// Tile 32c x 64n; phase2 writes bf16x8 (16B) per plane.
__global__ __launch_bounds__(256) void t_prep(
    const float* __restrict__ src,
    short* __restrict__ dhi, short* __restrict__ dlo)
{
    __shared__ float Ts[32][65];
    const int n0 = blockIdx.x * 64;   // grid.x = 196
    const int c0 = blockIdx.y * 32;   // grid.y = 8
    const int b  = blockIdx.z;
    const int tid = threadIdx.x;
    const int ln  = tid & 63;         // n offset (read) / n (write)
    const int wr  = tid >> 6;         // 0..3

#pragma unroll
    for (int i = 0; i < 8; ++i) {
        const int cc = wr * 8 + i;    // 0..31
        Ts[cc][ln] = src[((size_t)b * CCH + c0 + cc) * HW + n0 + ln];
    }
    __syncthreads();

    const int oct = wr;               // c-octet 0..3
    float f[8];
#pragma unroll
    for (int e = 0; e < 8; ++e) f[e] = Ts[oct * 8 + e][ln];
    bf16x8 h, l;
#pragma unroll
    for (int e = 0; e < 8; ++e) {
        unsigned short hb = f2bf_rne(f[e]);
        h[e] = (short)hb;
        l[e] = (short)f2bf_rne(f[e] - bf2f(hb));
    }
    const size_t o = ((size_t)b * HW + n0 + ln) * CCH + c0 + oct * 8;
    *(bf16x8*)&dhi[o] = h;
    *(bf16x8*)&dlo[o] = l;
}

// ---------------- main conv (r7, validated) ----------------
__global__ __launch_bounds__(256, 2) void conv_dbuf(
    const short* __restrict__ Whi, const short* __restrict__ Wlo,
    const short* __restrict__ Xthi, const short* __restrict__ Xtlo,
    float* __restrict__ Yout, const float* __restrict__ Res)
{
    const int bm  = blockIdx.x;
    const int bn  = blockIdx.y;
    const int b   = blockIdx.z;
    const int tid = threadIdx.x;
    const int lane = tid & 63, wid = tid >> 6;
    const int wr = wid >> 1, wc = wid & 1;
    const int fr = lane & 15, fg = lane >> 4;

    __shared__ __align__(16) short As[2][2][128 * 32];
    __shared__ __align__(16) short Bs[2][2][128 * 32];

    f32x4 acc[4][4];
#pragma unroll
    for (int m = 0; m < 4; ++m)
#pragma unroll
        for (int nf = 0; nf < 4; ++nf) acc[m][nf] = (f32x4){0.f, 0.f, 0.f, 0.f};

    const int srow  = lane >> 2;
    const int sslot = lane & 3;
    const int scol  = ((sslot ^ ((srow >> 1) & 3)) << 3);

    const size_t wbase = (size_t)bm * 128 * CCH;
    const size_t xbase = ((size_t)b * HW + (size_t)bn * 128) * CCH;

    auto STAGE = [&](int bi, int t) {
        const int k0 = t * 32;
#pragma unroll
        for (int j = 0; j < 2; ++j) {
            const int ch  = wid * 2 + j;
            const int row = ch * 16 + srow;
            const size_t wo = wbase + (size_t)row * CCH + k0 + scol;
            const size_t xo = xbase + (size_t)row * CCH + k0 + scol;
            __builtin_amdgcn_global_load_lds((gm_cv*)(Whi + wo),  (lds_v*)&As[bi][0][ch * 512], 16, 0, 0);
            __builtin_amdgcn_global_load_lds((gm_cv*)(Wlo + wo),  (lds_v*)&As[bi][1][ch * 512], 16, 0, 0);
            __builtin_amdgcn_global_load_lds((gm_cv*)(Xthi + xo), (lds_v*)&Bs[bi][0][ch * 512], 16, 0, 0);
            __builtin_amdgcn_global_load_lds((gm_cv*)(Xtlo + xo), (lds_v*)&Bs[bi][1][ch * 512], 16, 0, 0);
        }
    };

    auto COMPUTE = [&](int bi) {
        bf16x8 ah[4], al[4], bh[4], bl[4];
#pragma unroll
        for (int m = 0; m < 4; ++m) {
            const int row = wr * 64 + m * 16 + fr;
            const int off = row * 32 + ((fg ^ ((fr >> 1) & 3)) << 3);
            ah[m] = *(const bf16x8*)&As[bi][0][off];
            al[m] = *(const bf16x8*)&As[bi][1][off];
        }
#pragma unroll
        for (int nf = 0; nf < 4; ++nf) {
            const int row = wc * 64 + nf * 16 + fr;
            const int off = row * 32 + ((fg ^ ((fr >> 1) & 3)) << 3);
            bh[nf] = *(const bf16x8*)&Bs[bi][0][off];
            bl[nf] = *(const bf16x8*)&Bs[bi][1][off];
        }
#pragma unroll
        for (int m = 0; m < 4; ++m)
#pragma unroll
            for (int nf = 0; nf < 4; ++nf) {
                acc[m][nf] = __builtin_amdgcn_mfma_f32_16x16x32_bf16(ah[m], bh[nf], acc[m][nf], 0, 0, 0);
                acc[m][nf] = __builtin_amdgcn_mfma_f32_16x16x32_bf16(ah[m], bl[nf], acc[m][nf], 0, 0, 0);
                acc[m][nf] = __builtin_amdgcn_mfma_f32_16x16x32_bf16(al[m], bh[nf], acc[m][nf], 0, 0, 0);
            }
    };

    STAGE(0, 0);
    int cur = 0;
    for (int t = 0; t < 7; ++t) {
        STAGE(cur ^ 1, t + 1);
        asm volatile("s_waitcnt vmcnt(8)" ::: "memory");
        __builtin_amdgcn_s_barrier();
        __builtin_amdgcn_sched_barrier(0);
        COMPUTE(cur);
        __builtin_amdgcn_s_barrier();
        cur ^= 1;
    }
    asm volatile("s_waitcnt vmcnt(0)" ::: "memory");
    __builtin_amdgcn_s_barrier();
    __builtin_amdgcn_sched_barrier(0);
    COMPUTE(cur);

#pragma unroll
    for (int m = 0; m < 4; ++m)
#pragma unroll
        for (int nf = 0; nf < 4; ++nf) {
            const int gcol = bn * 128 + wc * 64 + nf * 16 + fr;
#pragma unroll
            for (int q = 0; q < 4; ++q) {
                const int grow = bm * 128 + wr * 64 + m * 16 + fg * 4 + q;
                const size_t idx = ((size_t)b * CCH + grow) * HW + gcol;
                float v = acc[m][nf][q];
                if (Res) v = fmaxf(v + Res[idx], 0.f);
                Yout[idx] = v;
            }
        }
}

// ---------------- MFMA attention ----------------
// One block per (b,c); 512 threads = 8 waves. Waves 0..6 each own 16 S-rows
// (fi = wid); wave 7 stages only. Split-bf16 (3-term) QK^T and PV.
// LDS: KT (reused for M) + VT, each [112 rows][128 k-slots] hi/lo,
// XOR slot-swizzle slot^=(row&7) (16B slots) to kill the 256B-row conflict.
__global__ __launch_bounds__(512) void attn_mfma(
    const float* __restrict__ Qg,
    const float* __restrict__ Kg,
    const float* __restrict__ Vg,
    float* __restrict__ Zg)
{
    const int bc   = blockIdx.x;
    const int tid  = threadIdx.x;
    const int lane = tid & 63;
    const int wid  = tid >> 6;
    const int t    = lane & 15;
    const int g    = lane >> 4;   // 0..3

    __shared__ __align__(16) short KTh[112 * 128];
    __shared__ __align__(16) short KTl[112 * 128];
    __shared__ __align__(16) short VTh[112 * 128];
    __shared__ __align__(16) short VTl[112 * 128];

    // zero-init all 4 planes (provides k/j >= 112 zero padding)
    for (int i = tid; i < 3584; i += 512) {
        *(short4v*)&KTh[i * 4] = (short4v){0, 0, 0, 0};
        *(short4v*)&KTl[i * 4] = (short4v){0, 0, 0, 0};
        *(short4v*)&VTh[i * 4] = (short4v){0, 0, 0, 0};
        *(short4v*)&VTl[i * 4] = (short4v){0, 0, 0, 0};
    }
    __syncthreads();

    const float* Qp = Qg + (size_t)bc * HW;
    const float* Kp = Kg + (size_t)bc * HW;
    const float* Vp = Vg + (size_t)bc * HW;

    // stage K^T: K[k][j] -> KT[j][swz(k)]   (coalesced reads, b16 LDS writes)
    for (int idx = tid; idx < HW; idx += 512) {
        const int k = idx / 112, j = idx - k * 112;
        const float v = Kp[idx];
        const unsigned short hb = f2bf_rne(v);
        const int col = (((k >> 3) ^ (j & 7)) << 3) | (k & 7);
        KTh[j * 128 + col] = (short)hb;
        KTl[j * 128 + col] = (short)f2bf_rne(v - bf2f(hb));
    }
    // stage V^T: V[j][w] -> VT[w][swz(j)]
    for (int idx = tid; idx < HW; idx += 512) {
        const int j = idx / 112, w = idx - j * 112;
        const float v = Vp[idx];
        const unsigned short hb = f2bf_rne(v);
        const int col = (((j >> 3) ^ (w & 7)) << 3) | (j & 7);
        VTh[w * 128 + col] = (short)hb;
        VTl[w * 128 + col] = (short)f2bf_rne(v - bf2f(hb));
    }

    // Q fragments in registers (A-operand, rows i = 16*wid + t)
    bf16x8 qh[4], ql[4];
    if (wid < 7) {
        const float* qrow = Qp + (size_t)(16 * wid + t) * 112;
#pragma unroll
        for (int s = 0; s < 4; ++s) {
            const int k0 = 32 * s + 8 * g;
            if (k0 < 112) {
                float4 a = *(const float4*)(qrow + k0);
                float4 b = *(const float4*)(qrow + k0 + 4);
                float f[8] = {a.x, a.y, a.z, a.w, b.x, b.y, b.z, b.w};
#pragma unroll
                for (int e = 0; e < 8; ++e) {
                    unsigned short hb = f2bf_rne(f[e]);
                    qh[s][e] = (short)hb;
                    ql[s][e] = (short)f2bf_rne(f[e] - bf2f(hb));
                }
            } else {
#pragma unroll
                for (int e = 0; e < 8; ++e) { qh[s][e] = 0; ql[s][e] = 0; }
            }
        }
    }
    __syncthreads();

    // ---- QK^T: S^(fi-block) = Q @ K ----
    f32x4 acc[7];
#pragma unroll
    for (int fj = 0; fj < 7; ++fj) acc[fj] = (f32x4){0.f, 0.f, 0.f, 0.f};

    if (wid < 7) {
#pragma unroll
        for (int s = 0; s < 4; ++s)
#pragma unroll
            for (int fj = 0; fj < 7; ++fj) {
                const int jr  = 16 * fj + t;
                const int off = jr * 128 + (((4 * s + g) ^ (jr & 7)) << 3);
                bf16x8 kh = *(const bf16x8*)&KTh[off];
                bf16x8 kl = *(const bf16x8*)&KTl[off];
                acc[fj] = __builtin_amdgcn_mfma_f32_16x16x32_bf16(qh[s], kh, acc[fj], 0, 0, 0);
                acc[fj] = __builtin_amdgcn_mfma_f32_16x16x32_bf16(qh[s], kl, acc[fj], 0, 0, 0);
                acc[fj] = __builtin_amdgcn_mfma_f32_16x16x32_bf16(ql[s], kh, acc[fj], 0, 0, 0);
            }

        // ---- softmax over j (7 frag-regs local + shfl over 16 t-lanes) ----
        float mx[4], sm[4];
#pragma unroll
        for (int q = 0; q < 4; ++q) {
            mx[q] = acc[0][q];
#pragma unroll
            for (int fj = 1; fj < 7; ++fj) mx[q] = fmaxf(mx[q], acc[fj][q]);
#pragma unroll
            for (int off = 1; off < 16; off <<= 1) mx[q] = fmaxf(mx[q], __shfl_xor(mx[q], off));
            sm[q] = 0.f;
        }
#pragma unroll
        for (int fj = 0; fj < 7; ++fj)
#pragma unroll
            for (int q = 0; q < 4; ++q) {
                float e = __expf(acc[fj][q] - mx[q]);
                acc[fj][q] = e;
                sm[q] += e;
            }
#pragma unroll
        for (int q = 0; q < 4; ++q) {
#pragma unroll
            for (int off = 1; off < 16; off <<= 1) sm[q] += __shfl_xor(sm[q], off);
            sm[q] = 1.0f / sm[q];
        }
#pragma unroll
        for (int fj = 0; fj < 7; ++fj)
#pragma unroll
            for (int q = 0; q < 4; ++q) acc[fj][q] *= sm[q];
    }

    __syncthreads();   // all waves done reading KT before M overwrites it

    // ---- write M (bf16 hi/lo) into KT region: rows i = wave's own rows ----
    if (wid < 7) {
#pragma unroll
        for (int fj = 0; fj < 7; ++fj)
#pragma unroll
            for (int q = 0; q < 4; ++q) {
                const float v = acc[fj][q];
                const int i = 16 * wid + 4 * g + q;
                const int j = 16 * fj + t;
                const int col = (((j >> 3) ^ (i & 7)) << 3) | (j & 7);
                const unsigned short hb = f2bf_rne(v);
                KTh[i * 128 + col] = (short)hb;
                KTl[i * 128 + col] = (short)f2bf_rne(v - bf2f(hb));
            }

        // ---- PV: Z = M @ V  (A = M rows (own), B = VT) ----
        f32x4 zc[7];
#pragma unroll
        for (int fw = 0; fw < 7; ++fw) zc[fw] = (f32x4){0.f, 0.f, 0.f, 0.f};
#pragma unroll
        for (int s = 0; s < 4; ++s) {
            const int ir   = 16 * wid + t;
            const int offm = ir * 128 + (((4 * s + g) ^ (ir & 7)) << 3);
            bf16x8 mh = *(const bf16x8*)&KTh[offm];
            bf16x8 ml = *(const bf16x8*)&KTl[offm];
#pragma unroll
            for (int fw = 0; fw < 7; ++fw) {
                const int vr  = 16 * fw + t;
                const int off = vr * 128 + (((4 * s + g) ^ (vr & 7)) << 3);
                bf16x8 bh = *(const bf16x8*)&VTh[off];
                bf16x8 bl = *(const bf16x8*)&VTl[off];
                zc[fw] = __builtin_amdgcn_mfma_f32_16x16x32_bf16(mh, bh, zc[fw], 0, 0, 0);
                zc[fw] = __builtin_amdgcn_mfma_f32_16x16x32_bf16(mh, bl, zc[fw], 0, 0, 0);
                zc[fw] = __builtin_amdgcn_mfma_f32_16x16x32_bf16(ml, bh, zc[fw], 0, 0, 0);
            }
        }

        float* Zp = Zg + (size_t)bc * HW;
#pragma unroll
        for (int fw = 0; fw < 7; ++fw)
#pragma unroll
            for (int q = 0; q < 4; ++q)
                Zp[(size_t)(16 * wid + 4 * g + q) * 112 + 16 * fw + t] = zc[fw][q];
    }
}

// ---------------- fallback path (r5-proven VALU attn + conv) ----------------
__global__ __launch_bounds__(256) void conv_mfma(
    const float* __restrict__ Wm,
    const float* __restrict__ Xin,
    float* __restrict__ Yout,
    const float* __restrict__ Res)
{
    const int bn  = blockIdx.x;
    const int bm  = blockIdx.y;
    const int b   = blockIdx.z;
    const int tid = threadIdx.x;

    __shared__ __align__(16) short As[2][128 * LDK];
    __shared__ __align__(16) short Bs[2][128 * LDK];

    const float* Xb = Xin + (size_t)b * CCH * HW;

    f32x4 acc[4][4];
#pragma unroll
    for (int m = 0; m < 4; ++m)
#pragma unroll
        for (int nf = 0; nf < 4; ++nf) acc[m][nf] = (f32x4){0.f, 0.f, 0.f, 0.f};

    const int ao  = tid >> 1;
    const int akh = (tid & 1) << 4;
    const int bnp = tid & 31;
    const int bcp = tid >> 5;

    const int lane = tid & 63;
    const int wid  = tid >> 6;
    const int wr = wid >> 1, wc = wid & 1;
    const int fr = lane & 15;
    const int fg = lane >> 4;

    for (int k0 = 0; k0 < CCH; k0 += 32) {
        {
            const float* wsrc = Wm + (size_t)(bm * 128 + ao) * CCH + k0 + akh;
            float4 w0 = *(const float4*)(wsrc + 0);
            float4 w1 = *(const float4*)(wsrc + 4);
            float4 w2 = *(const float4*)(wsrc + 8);
            float4 w3 = *(const float4*)(wsrc + 12);
            float wf[16] = {w0.x, w0.y, w0.z, w0.w, w1.x, w1.y, w1.z, w1.w,
                            w2.x, w2.y, w2.z, w2.w, w3.x, w3.y, w3.z, w3.w};
            bf16x8 h0, h1, l0, l1;
#pragma unroll
            for (int i = 0; i < 8; ++i) {
                unsigned short hb = f2bf_rne(wf[i]);
                h0[i] = (short)hb;
                l0[i] = (short)f2bf_rne(wf[i] - bf2f(hb));
            }
#pragma unroll
            for (int i = 0; i < 8; ++i) {
                unsigned short hb = f2bf_rne(wf[8 + i]);
                h1[i] = (short)hb;
                l1[i] = (short)f2bf_rne(wf[8 + i] - bf2f(hb));
            }
            *(bf16x8*)&As[0][ao * LDK + akh]     = h0;
            *(bf16x8*)&As[0][ao * LDK + akh + 8] = h1;
            *(bf16x8*)&As[1][ao * LDK + akh]     = l0;
            *(bf16x8*)&As[1][ao * LDK + akh + 8] = l1;
        }
        {
            const float* xsrc = Xb + (size_t)(k0 + bcp * 4) * HW + (size_t)bn * 128 + bnp * 4;
            float4 r0 = *(const float4*)(xsrc);
            float4 r1 = *(const float4*)(xsrc + HW);
            float4 r2 = *(const float4*)(xsrc + 2 * HW);
            float4 r3 = *(const float4*)(xsrc + 3 * HW);
            float rf[4][4] = {{r0.x, r0.y, r0.z, r0.w},
                              {r1.x, r1.y, r1.z, r1.w},
                              {r2.x, r2.y, r2.z, r2.w},
                              {r3.x, r3.y, r3.z, r3.w}};
#pragma unroll
            for (int j = 0; j < 4; ++j) {
                short4v hv, lv;
#pragma unroll
                for (int rr = 0; rr < 4; ++rr) {
                    unsigned short hb = f2bf_rne(rf[rr][j]);
                    hv[rr] = (short)hb;
                    lv[rr] = (short)f2bf_rne(rf[rr][j] - bf2f(hb));
                }
                *(short4v*)&Bs[0][(bnp * 4 + j) * LDK + bcp * 4] = hv;
                *(short4v*)&Bs[1][(bnp * 4 + j) * LDK + bcp * 4] = lv;
            }
        }
        __syncthreads();

        bf16x8 ah[4], al[4], bh[4], bl[4];
#pragma unroll
        for (int m = 0; m < 4; ++m) {
            const int off = (wr * 64 + m * 16 + fr) * LDK + fg * 8;
            ah[m] = *(const bf16x8*)&As[0][off];
            al[m] = *(const bf16x8*)&As[1][off];
        }
#pragma unroll
        for (int nf = 0; nf < 4; ++nf) {
            const int off = (wc * 64 + nf * 16 + fr) * LDK + fg * 8;
            bh[nf] = *(const bf16x8*)&Bs[0][off];
            bl[nf] = *(const bf16x8*)&Bs[1][off];
        }
#pragma unroll
        for (int m = 0; m < 4; ++m)
#pragma unroll
            for (int nf = 0; nf < 4; ++nf) {
                acc[m][nf] = __builtin_amdgcn_mfma_f32_16x16x32_bf16(ah[m], bh[nf], acc[m][nf], 0, 0, 0);
                acc[m][nf] = __builtin_amdgcn_mfma_f32_16x16x32_bf16(ah[m], bl[nf], acc[m][nf], 0, 0, 0);
                acc[m][nf] = __builtin_amdgcn_mfma_f32_16x16x32_bf16(al[m], bh[nf], acc[m][nf], 0, 0, 0);
            }
        __syncthreads();
    }

#pragma unroll
    for (int m = 0; m < 4; ++m)
#pragma unroll
        for (int nf = 0; nf < 4; ++nf) {
            const int gcol = bn * 128 + wc * 64 + nf * 16 + fr;
#pragma unroll
            for (int q = 0; q < 4; ++q) {
                const int grow = bm * 128 + wr * 64 + m * 16 + fg * 4 + q;
                const size_t idx = ((size_t)b * CCH + grow) * HW + gcol;
                float v = acc[m][nf][q];
                if (Res) v = fmaxf(v + Res[idx], 0.f);
                Yout[idx] = v;
            }
        }
}

__global__ __launch_bounds__(512) void attn_valu(
    const float* __restrict__ Qg,
    const float* __restrict__ Kg,
    const float* __restrict__ Vg,
    float* __restrict__ Zg)
{
    const int bc  = blockIdx.x;
    const int tid = threadIdx.x;
    const int tx  = tid & 15;
    const int ty  = tid >> 4;

    __shared__ float Qs[HH][116];
    __shared__ float Ks[HH][116];
    __shared__ float Vs[HH][116];

    const float* Qp = Qg + (size_t)bc * HW;
    const float* Kp = Kg + (size_t)bc * HW;
    const float* Vp = Vg + (size_t)bc * HW;

    for (int idx = tid; idx < HW / 4; idx += 512) {
        int row = idx / 28;
        int c4  = (idx % 28) * 4;
        *(float4*)&Qs[row][c4] = *(const float4*)(Qp + row * HH + c4);
        *(float4*)&Ks[row][c4] = *(const float4*)(Kp + row * HH + c4);
        *(float4*)&Vs[row][c4] = *(const float4*)(Vp + row * HH + c4);
    }
    __syncthreads();

    const bool act = (ty < 28);
    const int i0 = ty * 4;
    const int j0 = tx * 7;

    float s[4][7];
    if (act) {
#pragma unroll
        for (int ii = 0; ii < 4; ++ii)
#pragma unroll
            for (int jj = 0; jj < 7; ++jj) s[ii][jj] = 0.f;
        for (int k = 0; k < HH; ++k) {
            float qv[4], kv[7];
#pragma unroll
            for (int ii = 0; ii < 4; ++ii) qv[ii] = Qs[i0 + ii][k];
#pragma unroll
            for (int jj = 0; jj < 7; ++jj) kv[jj] = Ks[k][j0 + jj];
#pragma unroll
            for (int ii = 0; ii < 4; ++ii)
#pragma unroll
                for (int jj = 0; jj < 7; ++jj)
                    s[ii][jj] = fmaf(qv[ii], kv[jj], s[ii][jj]);
        }
#pragma unroll
        for (int ii = 0; ii < 4; ++ii) {
            float mx = s[ii][0];
#pragma unroll
            for (int jj = 1; jj < 7; ++jj) mx = fmaxf(mx, s[ii][jj]);
#pragma unroll
            for (int off = 1; off < 16; off <<= 1) mx = fmaxf(mx, __shfl_xor(mx, off));
            float sum = 0.f;
#pragma unroll
            for (int jj = 0; jj < 7; ++jj) {
                float e = __expf(s[ii][jj] - mx);
                s[ii][jj] = e;
                sum += e;
            }
#pragma unroll
            for (int off = 1; off < 16; off <<= 1) sum += __shfl_xor(sum, off);
            float inv = 1.0f / sum;
#pragma unroll
            for (int jj = 0; jj < 7; ++jj) s[ii][jj] *= inv;
        }
    }

    __syncthreads();
    if (act) {
#pragma unroll
        for (int ii = 0; ii < 4; ++ii)
#pragma unroll
            for (int jj = 0; jj < 7; ++jj)
                Qs[i0 + ii][j0 + jj] = s[ii][jj];
    }
    __syncthreads();

    if (act) {
        float z[4][7];
#pragma unroll
        for (int ii = 0; ii < 4; ++ii)
#pragma unroll
            for (int ww = 0; ww < 7; ++ww) z[ii][ww] = 0.f;
        for (int j = 0; j < HH; ++j) {
            float mv[4], vv[7];
#pragma unroll
            for (int ii = 0; ii < 4; ++ii) mv[ii] = Qs[i0 + ii][j];
#pragma unroll
            for (int ww = 0; ww < 7; ++ww) vv[ww] = Vs[j][j0 + ww];
#pragma unroll
            for (int ii = 0; ii < 4; ++ii)
#pragma unroll
                for (int ww = 0; ww < 7; ++ww)
                    z[ii][ww] = fmaf(mv[ii], vv[ww], z[ii][ww]);
        }
        float* Zp = Zg + (size_t)bc * HW;
#pragma unroll
        for (int ii = 0; ii < 4; ++ii)
#pragma unroll
            for (int ww = 0; ww < 7; ++ww)
                Zp[(i0 + ii) * HH + j0 + ww] = z[ii][ww];
    }
}

extern "C" void kernel_launch(void* const* d_in, const int* in_sizes, int n_in,
                              void* d_out, int out_size, void* d_ws, size_t ws_size,
                              hipStream_t stream) {
    const float* x  = (const float*)d_in[0];
    const float* y  = (const float*)d_in[1];
    const float* WQ = (const float*)d_in[2];
    const float* WK = (const float*)d_in[3];
    const float* WV = (const float*)d_in[4];
    const float* WZ = (const float*)d_in[5];
    float* out = (float*)d_out;

    const size_t n = (size_t)BB * CCH * HW;
    const size_t S_BYTES = n * 4;
    const size_t NEED = 3 * S_BYTES + (size_t)4 * CCH * CCH * 2 * sizeof(short);

    if (ws_size >= NEED) {
        short* At_hi = (short*)d_ws;
        short* At_lo = At_hi + n;
        float* Kb = (float*)((char*)d_ws + S_BYTES);
        float* Vb = (float*)((char*)d_ws + 2 * S_BYTES);
        short* Wb = (short*)((char*)d_ws + 3 * S_BYTES);
        float* Qb = out;
        float* Zb = Kb;

        dim3 tgrid(HW / 64, CCH / 32, BB);
        dim3 cgrid(2, 98, 8);

        w_prep<<<dim3(32, 4), 256, 0, stream>>>(WQ, WK, WV, WZ, Wb);
        t_prep<<<tgrid, 256, 0, stream>>>(x, At_hi, At_lo);
        conv_dbuf<<<cgrid, 256, 0, stream>>>(Wb, Wb + 65536, At_hi, At_lo, Qb, nullptr);
        t_prep<<<tgrid, 256, 0, stream>>>(y, At_hi, At_lo);
        conv_dbuf<<<cgrid, 256, 0, stream>>>(Wb + 131072, Wb + 131072 + 65536, At_hi, At_lo, Kb, nullptr);
        conv_dbuf<<<cgrid, 256, 0, stream>>>(Wb + 262144, Wb + 262144 + 65536, At_hi, At_lo, Vb, nullptr);
        attn_mfma<<<dim3(2048), 512, 0, stream>>>(Qb, Kb, Vb, Zb);
        t_prep<<<tgrid, 256, 0, stream>>>(Zb, At_hi, At_lo);
        conv_dbuf<<<cgrid, 256, 0, stream>>>(Wb + 393216, Wb + 393216 + 65536, At_hi, At_lo, out, x);
    } else {
        float* Kb = (float*)d_ws;
        float* Vb = Kb + n;
        float* Zb = Kb;
        float* Qb = out;
        dim3 grid(98, 2, 8);
        conv_mfma<<<grid, 256, 0, stream>>>(WQ, x, Qb, nullptr);
        conv_mfma<<<grid, 256, 0, stream>>>(WK, y, Kb, nullptr);
        conv_mfma<<<grid, 256, 0, stream>>>(WV, y, Vb, nullptr);
        attn_valu<<<dim3(2048), 512, 0, stream>>>(Qb, Kb, Vb, Zb);
        conv_mfma<<<grid, 256, 0, stream>>>(WZ, Zb, out, x);
    }
}